// Round 12
// baseline (260.214 us; speedup 1.0000x reference)
//
#include <hip/hip_runtime.h>
#include <hip/hip_fp16.h>

namespace {
constexpr int NN   = 10000;   // nodes
constexpr int NE   = 640000;  // edges
constexpr int INC  = 128;     // input channels
constexpr int HIDC = 256;     // hidden channels
constexpr int OUTC = 10;      // output channels
constexpr int NG   = 64;      // graphs
constexpr int PP   = 8;       // pooling partials per graph

// radix-partition CSR build
constexpr int NB     = 157;       // dst buckets of 64 nodes (bucket = dst>>6)
constexpr int G1     = 256;       // partition blocks
constexpr int CHUNK1 = NE / G1;   // 2500 edges per partition block
constexpr int CAPB   = 64;        // per (block,bucket) fragment cap (mean 16, +12 sigma)
constexpr int LCAP   = 5120;      // place LDS record cache (bucket mean 4076, +16 sigma)
}

typedef __attribute__((ext_vector_type(8))) short short8;
typedef __attribute__((ext_vector_type(4))) float f32x4;

__device__ __forceinline__ ushort f2bf(float f) {
    uint u = __float_as_uint(f);
    uint r = u + 0x7FFFu + ((u >> 16) & 1u);   // RNE
    return (ushort)(r >> 16);
}
__device__ __forceinline__ float bf2f(ushort u) {
    return __uint_as_float(((uint)u) << 16);
}
__device__ __forceinline__ float rec_w(uint rec) {
    return __half2float(__ushort_as_half((ushort)(rec & 0xFFFFu)));
}

// ---- CSR pass 1: partition edges into block-private per-bucket fragments ----
// Fused tail: x and W1/W2/W3 fp32 -> bf16.
__global__ __launch_bounds__(256) void partition_kernel(const int* __restrict__ ei,
                                                        const float* __restrict__ ew,
                                                        uint2* __restrict__ stag,
                                                        int* __restrict__ cnts,
                                                        int* __restrict__ cnts_T,
                                                        const float* __restrict__ x,
                                                        ushort* __restrict__ xb,
                                                        const float* __restrict__ W1,
                                                        ushort* __restrict__ w1b,
                                                        const float* __restrict__ W2,
                                                        ushort* __restrict__ w2b,
                                                        const float* __restrict__ W3,
                                                        ushort* __restrict__ w3b) {
    __shared__ int lcnt[NB];
    const int t = threadIdx.x, g = blockIdx.x;
    for (int i = t; i < NB; i += 256) lcnt[i] = 0;
    __syncthreads();
    const int base = g * CHUNK1;
    for (int i = t; i < CHUNK1; i += 256) {
        const int e = base + i;
        const int dst = ei[NE + e];
        const int src = ei[e];
        const ushort hw = __half_as_ushort(__float2half(ew[e]));
        const int bk = dst >> 6;
        const int idx = atomicAdd(&lcnt[bk], 1);
        if (idx < CAPB)
            stag[((size_t)g * NB + bk) * CAPB + idx] =
                make_uint2(((uint)src << 16) | (uint)hw, (uint)dst);
    }
    __syncthreads();
    for (int i = t; i < NB; i += 256) {
        const int c = min(lcnt[i], CAPB);
        cnts[g * NB + i] = c;          // g-major: read by place foff scan
        cnts_T[i * G1 + g] = c;        // b-major: contiguous rows for bucket totals
    }
    // fused conversions (grid-stride, independent of staging)
    const int gt = g * 256 + t, gs = G1 * 256;
    {
        const int n4 = NN * INC / 4;
        for (int i = gt; i < n4; i += gs) {
            float4 v = ((const float4*)x)[i];
            ushort4 o; o.x = f2bf(v.x); o.y = f2bf(v.y); o.z = f2bf(v.z); o.w = f2bf(v.w);
            ((ushort4*)xb)[i] = o;
        }
    }
    {
        const int n4 = HIDC * INC / 4;
        for (int i = gt; i < n4; i += gs) {
            float4 v = ((const float4*)W1)[i];
            ushort4 o; o.x = f2bf(v.x); o.y = f2bf(v.y); o.z = f2bf(v.z); o.w = f2bf(v.w);
            ((ushort4*)w1b)[i] = o;
        }
    }
    {
        const int n4 = HIDC * HIDC / 4;
        for (int i = gt; i < n4; i += gs) {
            float4 v = ((const float4*)W2)[i];
            ushort4 o; o.x = f2bf(v.x); o.y = f2bf(v.y); o.z = f2bf(v.z); o.w = f2bf(v.w);
            ((ushort4*)w2b)[i] = o;
            float4 v3 = ((const float4*)W3)[i];
            ushort4 o3; o3.x = f2bf(v3.x); o3.y = f2bf(v3.y); o3.z = f2bf(v3.z); o3.w = f2bf(v3.w);
            ((ushort4*)w3b)[i] = o3;
        }
    }
}

// ---- CSR pass 2: per-bucket counting sort (fused bucket prefix) ----
__global__ __launch_bounds__(1024) void place_kernel(const uint2* __restrict__ stag,
                                                     const int* __restrict__ cnts,
                                                     const int* __restrict__ cnts_T,
                                                     int* __restrict__ row_start,
                                                     uint* __restrict__ erec) {
    const int b = blockIdx.x;
    const int t = threadIdx.x;
    __shared__ int part[256];
    __shared__ int foff[G1 + 1];
    __shared__ int h[64];
    __shared__ int curl[64];
    __shared__ uint2 srec[LCAP];

    // Phase 0: bucket totals -> exclusive prefix -> bs
    {
        int s = 0;
        if (t < NB) {
            const int4* r = (const int4*)(cnts_T + (size_t)t * G1);
#pragma unroll 8
            for (int i = 0; i < G1 / 4; i++) {
                int4 v = r[i];
                s += v.x + v.y + v.z + v.w;
            }
        }
        if (t < 256) part[t] = s;
        __syncthreads();
        for (int off = 1; off < 256; off <<= 1) {
            int v = 0;
            if (t < 256 && t >= off) v = part[t - off];
            __syncthreads();
            if (t < 256) part[t] += v;
            __syncthreads();
        }
    }
    const int bs = (b == 0) ? 0 : part[b - 1];
    if (b == 0 && t == 0) row_start[NN] = part[NB - 1];
    __syncthreads();

    // Phase 1: fragment offsets within this bucket
    {
        int c = 0;
        if (t < 256) c = cnts[t * NB + b];
        if (t < 256) part[t] = c;
        if (t < 64) h[t] = 0;
        __syncthreads();
        for (int off = 1; off < 256; off <<= 1) {
            int v = 0;
            if (t < 256 && t >= off) v = part[t - off];
            __syncthreads();
            if (t < 256) part[t] += v;
            __syncthreads();
        }
        if (t < 256) foff[t] = part[t] - c;
        if (t == 0) foff[G1] = part[255];
        __syncthreads();
    }
    const int Rb = foff[G1];

    // Phase 2: records -> LDS cache + dst_low histogram
    for (int r = t; r < Rb; r += 1024) {
        int lo = 0, hi = G1;
        while (hi - lo > 1) { int mid = (lo + hi) >> 1; if (foff[mid] <= r) lo = mid; else hi = mid; }
        uint2 rec = stag[((size_t)lo * NB + b) * CAPB + (r - foff[lo])];
        if (r < LCAP) srec[r] = rec;
        atomicAdd(&h[rec.y & 63], 1);
    }
    __syncthreads();

    // Phase 3: scan h -> node offsets; emit row_start
    {
        const int hv = (t < 64) ? h[t] : 0;
        if (t < 256) part[t] = (t < 64) ? hv : 0;
        __syncthreads();
        for (int off = 1; off < 64; off <<= 1) {
            int v = 0;
            if (t < 256 && t >= off) v = part[t - off];
            __syncthreads();
            if (t < 256) part[t] += v;
            __syncthreads();
        }
        if (t < 64) {
            const int excl = part[t] - hv;
            const int node = b * 64 + t;
            if (node < NN) row_start[node] = bs + excl;
            curl[t] = excl;
        }
        __syncthreads();
    }

    // Phase 4: place records
    for (int r = t; r < Rb; r += 1024) {
        uint2 rec;
        if (r < LCAP) rec = srec[r];
        else {
            int lo = 0, hi = G1;
            while (hi - lo > 1) { int mid = (lo + hi) >> 1; if (foff[mid] <= r) lo = mid; else hi = mid; }
            rec = stag[((size_t)lo * NB + b) * CAPB + (r - foff[lo])];
        }
        const int pos = bs + atomicAdd(&curl[rec.y & 63], 1);
        erec[pos] = rec.x;
    }
}

// ---- aggregation gather, full row (F=128); masked U-batches, no scalar tail ----
template <int F>
__global__ __launch_bounds__(256) void gather_bf16_kernel(const int* __restrict__ row_start,
                                                          const uint* __restrict__ erec,
                                                          const ushort* __restrict__ x,
                                                          ushort* __restrict__ out) {
    constexpr int VEC = F / 64;
    constexpr int U = 16;
    const int n = blockIdx.x * 4 + (threadIdx.x >> 6);
    const int lane = threadIdx.x & 63;
    if (n >= NN) return;
    const int beg = row_start[n];
    const int end = row_start[n + 1];
    const size_t loff = (size_t)lane * VEC;

    float acc[VEC];
    {
        ushort v[VEC];
        if (VEC == 4) *(ushort4*)v = *(const ushort4*)(x + (size_t)n * F + loff);
        else          *(ushort2*)v = *(const ushort2*)(x + (size_t)n * F + loff);
#pragma unroll
        for (int i = 0; i < VEC; i++) acc[i] = bf2f(v[i]);
    }

    for (int e = beg; e < end; e += U) {
        uint rec[U];
        float w[U];
#pragma unroll
        for (int u = 0; u < U; u++) {
            const int idx = e + u;
            const bool ok = idx < end;
            rec[u] = erec[ok ? idx : (end - 1)];
            w[u] = ok ? rec_w(rec[u]) : 0.0f;
        }
        ushort v[U][VEC];
#pragma unroll
        for (int u = 0; u < U; u++) {
            const ushort* r = x + (size_t)(rec[u] >> 16) * F + loff;
            if (VEC == 4) *(ushort4*)v[u] = *(const ushort4*)r;
            else          *(ushort2*)v[u] = *(const ushort2*)r;
        }
#pragma unroll
        for (int u = 0; u < U; u++) {
#pragma unroll
            for (int i = 0; i < VEC; i++) acc[i] += w[u] * bf2f(v[u][i]);
        }
    }

    ushort o[VEC];
#pragma unroll
    for (int i = 0; i < VEC; i++) o[i] = f2bf(acc[i]);
    if (VEC == 4) *(ushort4*)(out + (size_t)n * F + loff) = *(ushort4*)o;
    else          *(ushort2*)(out + (size_t)n * F + loff) = *(ushort2*)o;
}

// ---- F=256 gather, one 128-channel half per DISPATCH (true L2 residency) ----
__global__ __launch_bounds__(256) void gather_bf16_half_kernel(const int* __restrict__ row_start,
                                                               const uint* __restrict__ erec,
                                                               const ushort* __restrict__ x,
                                                               ushort* __restrict__ out,
                                                               int half) {
    constexpr int U = 16;
    const int n = blockIdx.x * 4 + (threadIdx.x >> 6);
    const int lane = threadIdx.x & 63;
    if (n >= NN) return;
    const int beg = row_start[n];
    const int end = row_start[n + 1];
    const size_t loff = (size_t)half * 128 + lane * 2;

    float acc0, acc1;
    {
        ushort2 v = *(const ushort2*)(x + (size_t)n * HIDC + loff);
        acc0 = bf2f(v.x);
        acc1 = bf2f(v.y);
    }

    for (int e = beg; e < end; e += U) {
        uint rec[U];
        float w[U];
#pragma unroll
        for (int u = 0; u < U; u++) {
            const int idx = e + u;
            const bool ok = idx < end;
            rec[u] = erec[ok ? idx : (end - 1)];
            w[u] = ok ? rec_w(rec[u]) : 0.0f;
        }
        ushort2 v[U];
#pragma unroll
        for (int u = 0; u < U; u++)
            v[u] = *(const ushort2*)(x + (size_t)(rec[u] >> 16) * HIDC + loff);
#pragma unroll
        for (int u = 0; u < U; u++) {
            acc0 += w[u] * bf2f(v[u].x);
            acc1 += w[u] * bf2f(v[u].y);
        }
    }

    ushort2 o;
    o.x = f2bf(acc0);
    o.y = f2bf(acc1);
    *(ushort2*)(out + (size_t)n * HIDC + loff) = o;
}

// ---- MFMA bf16 GEMM: C[M,256] = relu(A[M,K] @ W[256,K]^T + bias), bf16 out ----
// W pre-converted to bf16.
template <int K>
__global__ __launch_bounds__(256) void mfma_gemm_kernel(const ushort* __restrict__ A,
                                                        const ushort* __restrict__ Wb,
                                                        const float* __restrict__ bias,
                                                        ushort* __restrict__ C, int M) {
    constexpr int LDW = K + 8;
    __shared__ ushort Ws[64 * LDW];
    const int tid = threadIdx.x;
    const int bm = blockIdx.x * 128;
    const int bn = blockIdx.y * 64;

    constexpr int CPR = K / 8;
    for (int idx = tid; idx < 64 * CPR; idx += 256) {
        int r = idx / CPR, c = idx % CPR;
        uint4 v = *(const uint4*)(Wb + (size_t)(bn + r) * K + c * 8);
        *(uint4*)(&Ws[r * LDW + c * 8]) = v;
    }
    __syncthreads();

    const int wave = tid >> 6;
    const int lane = tid & 63;
    const int lrow = lane & 15;
    const int lq   = lane >> 4;
    const int m0 = bm + wave * 32;

    f32x4 acc[2][4] = {};
    const int r0 = min(m0 + lrow, M - 1);
    const int r1 = min(m0 + 16 + lrow, M - 1);

    for (int k0 = 0; k0 < K; k0 += 32) {
        const int kk = k0 + lq * 8;
        short8 a0 = *(const short8*)(A + (size_t)r0 * K + kk);
        short8 a1 = *(const short8*)(A + (size_t)r1 * K + kk);
        short8 b[4];
#pragma unroll
        for (int j = 0; j < 4; j++)
            b[j] = *(const short8*)(&Ws[(j * 16 + lrow) * LDW + kk]);
#pragma unroll
        for (int j = 0; j < 4; j++) {
            acc[0][j] = __builtin_amdgcn_mfma_f32_16x16x32_bf16(a0, b[j], acc[0][j], 0, 0, 0);
            acc[1][j] = __builtin_amdgcn_mfma_f32_16x16x32_bf16(a1, b[j], acc[1][j], 0, 0, 0);
        }
    }

#pragma unroll
    for (int sub = 0; sub < 2; sub++) {
#pragma unroll
        for (int j = 0; j < 4; j++) {
            const int gn = bn + j * 16 + lrow;
            const float bv = bias[gn];
#pragma unroll
            for (int i = 0; i < 4; i++) {
                const int gm = m0 + sub * 16 + lq * 4 + i;
                if (gm < M) {
                    float v = acc[sub][j][i] + bv;
                    v = fmaxf(v, 0.0f);
                    C[(size_t)gm * HIDC + gn] = f2bf(v);
                }
            }
        }
    }
}

__device__ __forceinline__ int lower_bound_batch(const int* __restrict__ batch, int val) {
    int lo = 0, hi = NN;
    while (lo < hi) {
        int mid = (lo + hi) >> 1;
        if (batch[mid] < val) lo = mid + 1;
        else hi = mid;
    }
    return lo;
}

// ---- segmented mean-pool stage 1: partial sums over bf16 h ----
__global__ __launch_bounds__(256) void pool_partial_kernel(const ushort* __restrict__ h,
                                                           const int* __restrict__ batch,
                                                           float* __restrict__ partials) {
    const int g = blockIdx.x;
    const int p = blockIdx.y;
    const int c = threadIdx.x;
    const int lo = lower_bound_batch(batch, g);
    const int hi = lower_bound_batch(batch, g + 1);
    const int cnt = hi - lo;
    const int chunk = (cnt + PP - 1) / PP;
    const int n0 = lo + p * chunk;
    const int n1 = min(hi, n0 + chunk);
    float sum = 0.0f;
    for (int n = n0; n < n1; n++) sum += bf2f(h[(size_t)n * HIDC + c]);
    partials[((size_t)g * PP + p) * HIDC + c] = sum;
}

// ---- stage 2: reduce partials, mean, head linear (fp32) ----
__global__ __launch_bounds__(256) void head_kernel(const float* __restrict__ partials,
                                                   const int* __restrict__ batch,
                                                   const float* __restrict__ Wl,
                                                   const float* __restrict__ bl,
                                                   float* __restrict__ out) {
    __shared__ float s[HIDC];
    const int g = blockIdx.x;
    const int c = threadIdx.x;
    const int lo = lower_bound_batch(batch, g);
    const int hi = lower_bound_batch(batch, g + 1);
    const float inv = 1.0f / fmaxf((float)(hi - lo), 1.0f);
    float sum = 0.0f;
#pragma unroll
    for (int p = 0; p < PP; p++) sum += partials[((size_t)g * PP + p) * HIDC + c];
    s[c] = sum * inv;
    __syncthreads();
    if (c < OUTC) {
        float acc = bl[c];
        for (int k = 0; k < HIDC; k++) acc += s[k] * Wl[(size_t)c * HIDC + k];
        out[(size_t)g * OUTC + c] = acc;
    }
}

extern "C" void kernel_launch(void* const* d_in, const int* in_sizes, int n_in,
                              void* d_out, int out_size, void* d_ws, size_t ws_size,
                              hipStream_t stream) {
    const float* x     = (const float*)d_in[0];
    const int*   ei    = (const int*)d_in[1];
    const int*   batch = (const int*)d_in[2];
    const float* ew    = (const float*)d_in[3];
    const float* W1    = (const float*)d_in[4];
    const float* b1    = (const float*)d_in[5];
    const float* W2    = (const float*)d_in[6];
    const float* b2    = (const float*)d_in[7];
    const float* W3    = (const float*)d_in[8];
    const float* b3    = (const float*)d_in[9];
    const float* Wl    = (const float*)d_in[10];
    const float* bl    = (const float*)d_in[11];

    // ---- workspace layout ----
    char* p = (char*)d_ws;
    uint2*  stag   = (uint2*)p;  p += (size_t)G1 * NB * CAPB * 8;   // 20.6 MB
    ushort* xb     = (ushort*)p; p += (size_t)NN * INC * 2;
    ushort* agg128 = (ushort*)p; p += (size_t)NN * INC * 2;
    ushort* agg256 = (ushort*)p; p += (size_t)NN * HIDC * 2;
    ushort* h      = (ushort*)p; p += (size_t)NN * HIDC * 2;
    ushort* w1b    = (ushort*)p; p += (size_t)HIDC * INC * 2;
    ushort* w2b    = (ushort*)p; p += (size_t)HIDC * HIDC * 2;
    ushort* w3b    = (ushort*)p; p += (size_t)HIDC * HIDC * 2;
    uint*   erec   = (uint*)p;   p += (size_t)NE * 4;
    float*  partials = (float*)p; p += (size_t)NG * PP * HIDC * 4;
    int*    cnts   = (int*)p;    p += (size_t)G1 * NB * 4;
    int*    cnts_T = (int*)p;    p += (size_t)NB * G1 * 4;
    int*    row_start = (int*)p; p += 40016;

    // ---- CSR build: radix partition (per call) ----
    partition_kernel<<<G1, 256, 0, stream>>>(ei, ew, stag, cnts, cnts_T, x, xb,
                                             W1, w1b, W2, w2b, W3, w3b);
    place_kernel<<<NB, 1024, 0, stream>>>(stag, cnts, cnts_T, row_start, erec);

    const int gather_grid = (NN + 3) / 4;
    dim3 gemm_grid((NN + 127) / 128, HIDC / 64);

    // ---- layer 1 (K=128) ----
    gather_bf16_kernel<INC><<<gather_grid, 256, 0, stream>>>(row_start, erec, xb, agg128);
    mfma_gemm_kernel<INC><<<gemm_grid, 256, 0, stream>>>(agg128, w1b, b1, h, NN);

    // ---- layer 2 (K=256): sequential halves for per-XCD L2 residency ----
    gather_bf16_half_kernel<<<gather_grid, 256, 0, stream>>>(row_start, erec, h, agg256, 0);
    gather_bf16_half_kernel<<<gather_grid, 256, 0, stream>>>(row_start, erec, h, agg256, 1);
    mfma_gemm_kernel<HIDC><<<gemm_grid, 256, 0, stream>>>(agg256, w2b, b2, h, NN);

    // ---- layer 3 (K=256) ----
    gather_bf16_half_kernel<<<gather_grid, 256, 0, stream>>>(row_start, erec, h, agg256, 0);
    gather_bf16_half_kernel<<<gather_grid, 256, 0, stream>>>(row_start, erec, h, agg256, 1);
    mfma_gemm_kernel<HIDC><<<gemm_grid, 256, 0, stream>>>(agg256, w3b, b3, h, NN);

    // ---- global mean pool + head ----
    pool_partial_kernel<<<dim3(NG, PP), 256, 0, stream>>>(h, batch, partials);
    head_kernel<<<NG, 256, 0, stream>>>(partials, batch, Wl, bl, (float*)d_out);
}

// Round 13
// 239.008 us; speedup vs baseline: 1.0887x; 1.0887x over previous
//
#include <hip/hip_runtime.h>
#include <hip/hip_fp16.h>

namespace {
constexpr int NN   = 10000;   // nodes
constexpr int NE   = 640000;  // edges
constexpr int INC  = 128;     // input channels
constexpr int HIDC = 256;     // hidden channels
constexpr int OUTC = 10;      // output channels
constexpr int NG   = 64;      // graphs
constexpr int PP   = 8;       // pooling partials per graph

// radix-partition CSR build
constexpr int NB     = 157;       // dst buckets of 64 nodes (bucket = dst>>6)
constexpr int G1     = 256;       // partition blocks
constexpr int CHUNK1 = NE / G1;   // 2500 edges per partition block
constexpr int CAPB   = 64;        // per (block,bucket) fragment cap (mean 16, +12 sigma)
constexpr int LCAP   = 5120;      // place LDS record cache (bucket mean 4076, +16 sigma)
}

typedef __attribute__((ext_vector_type(8))) short short8;
typedef __attribute__((ext_vector_type(4))) float f32x4;

__device__ __forceinline__ ushort f2bf(float f) {
    uint u = __float_as_uint(f);
    uint r = u + 0x7FFFu + ((u >> 16) & 1u);   // RNE
    return (ushort)(r >> 16);
}
__device__ __forceinline__ float bf2f(ushort u) {
    return __uint_as_float(((uint)u) << 16);
}
__device__ __forceinline__ float rec_w(uint rec) {
    return __half2float(__ushort_as_half((ushort)(rec & 0xFFFFu)));
}

// ---- CSR pass 1: partition edges into block-private per-bucket fragments ----
// Fused tail: x and W1/W2/W3 fp32 -> bf16 (grid-stride).
__global__ __launch_bounds__(256) void partition_kernel(const int* __restrict__ ei,
                                                        const float* __restrict__ ew,
                                                        uint2* __restrict__ stag,
                                                        int* __restrict__ cnts,
                                                        int* __restrict__ cnts_T,
                                                        const float* __restrict__ x,
                                                        ushort* __restrict__ xb,
                                                        const float* __restrict__ W1,
                                                        ushort* __restrict__ w1b,
                                                        const float* __restrict__ W2,
                                                        ushort* __restrict__ w2b,
                                                        const float* __restrict__ W3,
                                                        ushort* __restrict__ w3b) {
    __shared__ int lcnt[NB];
    const int t = threadIdx.x, g = blockIdx.x;
    for (int i = t; i < NB; i += 256) lcnt[i] = 0;
    __syncthreads();
    const int base = g * CHUNK1;
    for (int i = t; i < CHUNK1; i += 256) {
        const int e = base + i;
        const int dst = ei[NE + e];
        const int src = ei[e];
        const ushort hw = __half_as_ushort(__float2half(ew[e]));
        const int bk = dst >> 6;
        const int idx = atomicAdd(&lcnt[bk], 1);
        if (idx < CAPB)
            stag[((size_t)g * NB + bk) * CAPB + idx] =
                make_uint2(((uint)src << 16) | (uint)hw, (uint)dst);
    }
    __syncthreads();
    for (int i = t; i < NB; i += 256) {
        const int c = min(lcnt[i], CAPB);
        cnts[g * NB + i] = c;          // g-major: read by place foff scan
        cnts_T[i * G1 + g] = c;        // b-major: contiguous rows for bucket totals
    }
    // fused conversions (independent of staging)
    const int gt = g * 256 + t, gs = G1 * 256;
    {
        const int n4 = NN * INC / 4;
        for (int i = gt; i < n4; i += gs) {
            float4 v = ((const float4*)x)[i];
            ushort4 o; o.x = f2bf(v.x); o.y = f2bf(v.y); o.z = f2bf(v.z); o.w = f2bf(v.w);
            ((ushort4*)xb)[i] = o;
        }
    }
    {
        const int n4 = HIDC * INC / 4;
        for (int i = gt; i < n4; i += gs) {
            float4 v = ((const float4*)W1)[i];
            ushort4 o; o.x = f2bf(v.x); o.y = f2bf(v.y); o.z = f2bf(v.z); o.w = f2bf(v.w);
            ((ushort4*)w1b)[i] = o;
        }
    }
    {
        const int n4 = HIDC * HIDC / 4;
        for (int i = gt; i < n4; i += gs) {
            float4 v = ((const float4*)W2)[i];
            ushort4 o; o.x = f2bf(v.x); o.y = f2bf(v.y); o.z = f2bf(v.z); o.w = f2bf(v.w);
            ((ushort4*)w2b)[i] = o;
            float4 v3 = ((const float4*)W3)[i];
            ushort4 o3; o3.x = f2bf(v3.x); o3.y = f2bf(v3.y); o3.z = f2bf(v3.z); o3.w = f2bf(v3.w);
            ((ushort4*)w3b)[i] = o3;
        }
    }
}

// ---- CSR pass 2: per-bucket counting sort (fused bucket prefix) ----
__global__ __launch_bounds__(1024) void place_kernel(const uint2* __restrict__ stag,
                                                     const int* __restrict__ cnts,
                                                     const int* __restrict__ cnts_T,
                                                     int* __restrict__ row_start,
                                                     uint* __restrict__ erec) {
    const int b = blockIdx.x;
    const int t = threadIdx.x;
    __shared__ int part[256];
    __shared__ int foff[G1 + 1];
    __shared__ int h[64];
    __shared__ int curl[64];
    __shared__ uint2 srec[LCAP];

    // Phase 0: bucket totals (contiguous int4 rows) -> exclusive prefix -> bs
    {
        int s = 0;
        if (t < NB) {
            const int4* r = (const int4*)(cnts_T + (size_t)t * G1);
#pragma unroll 8
            for (int i = 0; i < G1 / 4; i++) {
                int4 v = r[i];
                s += v.x + v.y + v.z + v.w;
            }
        }
        if (t < 256) part[t] = s;
        __syncthreads();
        for (int off = 1; off < 256; off <<= 1) {
            int v = 0;
            if (t < 256 && t >= off) v = part[t - off];
            __syncthreads();
            if (t < 256) part[t] += v;
            __syncthreads();
        }
    }
    const int bs = (b == 0) ? 0 : part[b - 1];
    if (b == 0 && t == 0) row_start[NN] = part[NB - 1];
    __syncthreads();

    // Phase 1: fragment offsets within this bucket (scan of cnts[:, b])
    {
        int c = 0;
        if (t < 256) c = cnts[t * NB + b];
        if (t < 256) part[t] = c;
        if (t < 64) h[t] = 0;
        __syncthreads();
        for (int off = 1; off < 256; off <<= 1) {
            int v = 0;
            if (t < 256 && t >= off) v = part[t - off];
            __syncthreads();
            if (t < 256) part[t] += v;
            __syncthreads();
        }
        if (t < 256) foff[t] = part[t] - c;
        if (t == 0) foff[G1] = part[255];
        __syncthreads();
    }
    const int Rb = foff[G1];

    // Phase 2: single global pass: records -> LDS cache + dst_low histogram
    for (int r = t; r < Rb; r += 1024) {
        int lo = 0, hi = G1;
        while (hi - lo > 1) { int mid = (lo + hi) >> 1; if (foff[mid] <= r) lo = mid; else hi = mid; }
        uint2 rec = stag[((size_t)lo * NB + b) * CAPB + (r - foff[lo])];
        if (r < LCAP) srec[r] = rec;
        atomicAdd(&h[rec.y & 63], 1);
    }
    __syncthreads();

    // Phase 3: scan h -> node offsets; emit row_start for this bucket's nodes
    {
        const int hv = (t < 64) ? h[t] : 0;
        if (t < 256) part[t] = (t < 64) ? hv : 0;
        __syncthreads();
        for (int off = 1; off < 64; off <<= 1) {
            int v = 0;
            if (t < 256 && t >= off) v = part[t - off];
            __syncthreads();
            if (t < 256) part[t] += v;
            __syncthreads();
        }
        if (t < 64) {
            const int excl = part[t] - hv;
            const int node = b * 64 + t;
            if (node < NN) row_start[node] = bs + excl;
            curl[t] = excl;
        }
        __syncthreads();
    }

    // Phase 4: place records (LDS-resident; global fallback for overflow)
    for (int r = t; r < Rb; r += 1024) {
        uint2 rec;
        if (r < LCAP) rec = srec[r];
        else {
            int lo = 0, hi = G1;
            while (hi - lo > 1) { int mid = (lo + hi) >> 1; if (foff[mid] <= r) lo = mid; else hi = mid; }
            rec = stag[((size_t)lo * NB + b) * CAPB + (r - foff[lo])];
        }
        const int pos = bs + atomicAdd(&curl[rec.y & 63], 1);
        erec[pos] = rec.x;
    }
}

// ---- aggregation gather, full row (used for F=128) ----
template <int F>
__global__ __launch_bounds__(256) void gather_bf16_kernel(const int* __restrict__ row_start,
                                                          const uint* __restrict__ erec,
                                                          const ushort* __restrict__ x,
                                                          ushort* __restrict__ out) {
    constexpr int VEC = F / 64;
    constexpr int U = 12;
    const int n = blockIdx.x * 4 + (threadIdx.x >> 6);
    const int lane = threadIdx.x & 63;
    if (n >= NN) return;
    const int beg = row_start[n];
    const int end = row_start[n + 1];
    const size_t loff = (size_t)lane * VEC;

    float acc[VEC];
    {
        ushort v[VEC];
        if (VEC == 4) *(ushort4*)v = *(const ushort4*)(x + (size_t)n * F + loff);
        else          *(ushort2*)v = *(const ushort2*)(x + (size_t)n * F + loff);
#pragma unroll
        for (int i = 0; i < VEC; i++) acc[i] = bf2f(v[i]);
    }

    int e = beg;
    for (; e + U <= end; e += U) {
        uint rec[U];
#pragma unroll
        for (int u = 0; u < U; u++) rec[u] = erec[e + u];
        ushort v[U][VEC];
#pragma unroll
        for (int u = 0; u < U; u++) {
            const ushort* r = x + (size_t)(rec[u] >> 16) * F + loff;
            if (VEC == 4) *(ushort4*)v[u] = *(const ushort4*)r;
            else          *(ushort2*)v[u] = *(const ushort2*)r;
        }
#pragma unroll
        for (int u = 0; u < U; u++) {
            const float w = rec_w(rec[u]);
#pragma unroll
            for (int i = 0; i < VEC; i++) acc[i] += w * bf2f(v[u][i]);
        }
    }
    for (; e < end; e++) {
        uint rec = erec[e];
        const float w = rec_w(rec);
        ushort v[VEC];
        const ushort* r = x + (size_t)(rec >> 16) * F + loff;
        if (VEC == 4) *(ushort4*)v = *(const ushort4*)r;
        else          *(ushort2*)v = *(const ushort2*)r;
#pragma unroll
        for (int i = 0; i < VEC; i++) acc[i] += w * bf2f(v[i]);
    }

    ushort o[VEC];
#pragma unroll
    for (int i = 0; i < VEC; i++) o[i] = f2bf(acc[i]);
    if (VEC == 4) *(ushort4*)(out + (size_t)n * F + loff) = *(ushort4*)o;
    else          *(ushort2*)(out + (size_t)n * F + loff) = *(ushort2*)o;
}

// ---- F=256 gather, column-split: blockIdx.y selects 128-channel half ----
__global__ __launch_bounds__(256) void gather_bf16_half_kernel(const int* __restrict__ row_start,
                                                               const uint* __restrict__ erec,
                                                               const ushort* __restrict__ x,
                                                               ushort* __restrict__ out) {
    constexpr int U = 16;
    const int n = blockIdx.x * 4 + (threadIdx.x >> 6);
    const int lane = threadIdx.x & 63;
    if (n >= NN) return;
    const int beg = row_start[n];
    const int end = row_start[n + 1];
    const size_t loff = (size_t)blockIdx.y * 128 + lane * 2;

    float acc0, acc1;
    {
        ushort2 v = *(const ushort2*)(x + (size_t)n * HIDC + loff);
        acc0 = bf2f(v.x);
        acc1 = bf2f(v.y);
    }

    int e = beg;
    for (; e + U <= end; e += U) {
        uint rec[U];
#pragma unroll
        for (int u = 0; u < U; u++) rec[u] = erec[e + u];
        ushort2 v[U];
#pragma unroll
        for (int u = 0; u < U; u++)
            v[u] = *(const ushort2*)(x + (size_t)(rec[u] >> 16) * HIDC + loff);
#pragma unroll
        for (int u = 0; u < U; u++) {
            const float w = rec_w(rec[u]);
            acc0 += w * bf2f(v[u].x);
            acc1 += w * bf2f(v[u].y);
        }
    }
    for (; e < end; e++) {
        uint rec = erec[e];
        const float w = rec_w(rec);
        ushort2 v = *(const ushort2*)(x + (size_t)(rec >> 16) * HIDC + loff);
        acc0 += w * bf2f(v.x);
        acc1 += w * bf2f(v.y);
    }

    ushort2 o;
    o.x = f2bf(acc0);
    o.y = f2bf(acc1);
    *(ushort2*)(out + (size_t)n * HIDC + loff) = o;
}

// ---- MFMA bf16 GEMM: C[M,256] = relu(A[M,K] @ W[256,K]^T + bias), bf16 out ----
// W pre-converted to bf16; staged as uint4.
template <int K>
__global__ __launch_bounds__(256) void mfma_gemm_kernel(const ushort* __restrict__ A,
                                                        const ushort* __restrict__ Wb,
                                                        const float* __restrict__ bias,
                                                        ushort* __restrict__ C, int M) {
    constexpr int LDW = K + 8;
    __shared__ ushort Ws[64 * LDW];
    const int tid = threadIdx.x;
    const int bm = blockIdx.x * 128;
    const int bn = blockIdx.y * 64;

    constexpr int CPR = K / 8;
    for (int idx = tid; idx < 64 * CPR; idx += 256) {
        int r = idx / CPR, c = idx % CPR;
        uint4 v = *(const uint4*)(Wb + (size_t)(bn + r) * K + c * 8);
        *(uint4*)(&Ws[r * LDW + c * 8]) = v;
    }
    __syncthreads();

    const int wave = tid >> 6;
    const int lane = tid & 63;
    const int lrow = lane & 15;
    const int lq   = lane >> 4;
    const int m0 = bm + wave * 32;

    f32x4 acc[2][4] = {};
    const int r0 = min(m0 + lrow, M - 1);
    const int r1 = min(m0 + 16 + lrow, M - 1);

    for (int k0 = 0; k0 < K; k0 += 32) {
        const int kk = k0 + lq * 8;
        short8 a0 = *(const short8*)(A + (size_t)r0 * K + kk);
        short8 a1 = *(const short8*)(A + (size_t)r1 * K + kk);
        short8 b[4];
#pragma unroll
        for (int j = 0; j < 4; j++)
            b[j] = *(const short8*)(&Ws[(j * 16 + lrow) * LDW + kk]);
#pragma unroll
        for (int j = 0; j < 4; j++) {
            acc[0][j] = __builtin_amdgcn_mfma_f32_16x16x32_bf16(a0, b[j], acc[0][j], 0, 0, 0);
            acc[1][j] = __builtin_amdgcn_mfma_f32_16x16x32_bf16(a1, b[j], acc[1][j], 0, 0, 0);
        }
    }

#pragma unroll
    for (int sub = 0; sub < 2; sub++) {
#pragma unroll
        for (int j = 0; j < 4; j++) {
            const int gn = bn + j * 16 + lrow;
            const float bv = bias[gn];
#pragma unroll
            for (int i = 0; i < 4; i++) {
                const int gm = m0 + sub * 16 + lq * 4 + i;
                if (gm < M) {
                    float v = acc[sub][j][i] + bv;
                    v = fmaxf(v, 0.0f);
                    C[(size_t)gm * HIDC + gn] = f2bf(v);
                }
            }
        }
    }
}

__device__ __forceinline__ int lower_bound_batch(const int* __restrict__ batch, int val) {
    int lo = 0, hi = NN;
    while (lo < hi) {
        int mid = (lo + hi) >> 1;
        if (batch[mid] < val) lo = mid + 1;
        else hi = mid;
    }
    return lo;
}

// ---- segmented mean-pool stage 1: partial sums over bf16 h ----
__global__ __launch_bounds__(256) void pool_partial_kernel(const ushort* __restrict__ h,
                                                           const int* __restrict__ batch,
                                                           float* __restrict__ partials) {
    const int g = blockIdx.x;
    const int p = blockIdx.y;
    const int c = threadIdx.x;
    const int lo = lower_bound_batch(batch, g);
    const int hi = lower_bound_batch(batch, g + 1);
    const int cnt = hi - lo;
    const int chunk = (cnt + PP - 1) / PP;
    const int n0 = lo + p * chunk;
    const int n1 = min(hi, n0 + chunk);
    float sum = 0.0f;
    for (int n = n0; n < n1; n++) sum += bf2f(h[(size_t)n * HIDC + c]);
    partials[((size_t)g * PP + p) * HIDC + c] = sum;
}

// ---- stage 2: reduce partials, mean, head linear (fp32) ----
__global__ __launch_bounds__(256) void head_kernel(const float* __restrict__ partials,
                                                   const int* __restrict__ batch,
                                                   const float* __restrict__ Wl,
                                                   const float* __restrict__ bl,
                                                   float* __restrict__ out) {
    __shared__ float s[HIDC];
    const int g = blockIdx.x;
    const int c = threadIdx.x;
    const int lo = lower_bound_batch(batch, g);
    const int hi = lower_bound_batch(batch, g + 1);
    const float inv = 1.0f / fmaxf((float)(hi - lo), 1.0f);
    float sum = 0.0f;
#pragma unroll
    for (int p = 0; p < PP; p++) sum += partials[((size_t)g * PP + p) * HIDC + c];
    s[c] = sum * inv;
    __syncthreads();
    if (c < OUTC) {
        float acc = bl[c];
        for (int k = 0; k < HIDC; k++) acc += s[k] * Wl[(size_t)c * HIDC + k];
        out[(size_t)g * OUTC + c] = acc;
    }
}

extern "C" void kernel_launch(void* const* d_in, const int* in_sizes, int n_in,
                              void* d_out, int out_size, void* d_ws, size_t ws_size,
                              hipStream_t stream) {
    const float* x     = (const float*)d_in[0];
    const int*   ei    = (const int*)d_in[1];
    const int*   batch = (const int*)d_in[2];
    const float* ew    = (const float*)d_in[3];
    const float* W1    = (const float*)d_in[4];
    const float* b1    = (const float*)d_in[5];
    const float* W2    = (const float*)d_in[6];
    const float* b2    = (const float*)d_in[7];
    const float* W3    = (const float*)d_in[8];
    const float* b3    = (const float*)d_in[9];
    const float* Wl    = (const float*)d_in[10];
    const float* bl    = (const float*)d_in[11];

    // ---- workspace layout ----
    char* p = (char*)d_ws;
    uint2*  stag   = (uint2*)p;  p += (size_t)G1 * NB * CAPB * 8;   // 20.6 MB
    ushort* xb     = (ushort*)p; p += (size_t)NN * INC * 2;
    ushort* agg128 = (ushort*)p; p += (size_t)NN * INC * 2;
    ushort* agg256 = (ushort*)p; p += (size_t)NN * HIDC * 2;
    ushort* h      = (ushort*)p; p += (size_t)NN * HIDC * 2;
    ushort* w1b    = (ushort*)p; p += (size_t)HIDC * INC * 2;
    ushort* w2b    = (ushort*)p; p += (size_t)HIDC * HIDC * 2;
    ushort* w3b    = (ushort*)p; p += (size_t)HIDC * HIDC * 2;
    uint*   erec   = (uint*)p;   p += (size_t)NE * 4;
    float*  partials = (float*)p; p += (size_t)NG * PP * HIDC * 4;
    int*    cnts   = (int*)p;    p += (size_t)G1 * NB * 4;
    int*    cnts_T = (int*)p;    p += (size_t)NB * G1 * 4;
    int*    row_start = (int*)p; p += 40016;

    // ---- CSR build: radix partition (per call) ----
    partition_kernel<<<G1, 256, 0, stream>>>(ei, ew, stag, cnts, cnts_T, x, xb,
                                             W1, w1b, W2, w2b, W3, w3b);
    place_kernel<<<NB, 1024, 0, stream>>>(stag, cnts, cnts_T, row_start, erec);

    const int gather_grid = (NN + 3) / 4;
    dim3 gemm_grid((NN + 127) / 128, HIDC / 64);

    // ---- layer 1 (K=128) ----
    gather_bf16_kernel<INC><<<gather_grid, 256, 0, stream>>>(row_start, erec, xb, agg128);
    mfma_gemm_kernel<INC><<<gemm_grid, 256, 0, stream>>>(agg128, w1b, b1, h, NN);

    // ---- layer 2 (K=256) ----
    gather_bf16_half_kernel<<<dim3(gather_grid, 2), 256, 0, stream>>>(row_start, erec, h, agg256);
    mfma_gemm_kernel<HIDC><<<gemm_grid, 256, 0, stream>>>(agg256, w2b, b2, h, NN);

    // ---- layer 3 (K=256) ----
    gather_bf16_half_kernel<<<dim3(gather_grid, 2), 256, 0, stream>>>(row_start, erec, h, agg256);
    mfma_gemm_kernel<HIDC><<<gemm_grid, 256, 0, stream>>>(agg256, w3b, b3, h, NN);

    // ---- global mean pool + head ----
    pool_partial_kernel<<<dim3(NG, PP), 256, 0, stream>>>(h, batch, partials);
    head_kernel<<<NG, 256, 0, stream>>>(partials, batch, Wl, bl, (float*)d_out);
}

// Round 14
// 237.105 us; speedup vs baseline: 1.0975x; 1.0080x over previous
//
#include <hip/hip_runtime.h>
#include <hip/hip_fp16.h>

namespace {
constexpr int NN   = 10000;   // nodes
constexpr int NE   = 640000;  // edges
constexpr int INC  = 128;     // input channels
constexpr int HIDC = 256;     // hidden channels
constexpr int OUTC = 10;      // output channels
constexpr int NG   = 64;      // graphs
constexpr int PP   = 8;       // pooling partials per graph

// radix-partition CSR build
constexpr int NB     = 157;       // dst buckets of 64 nodes (bucket = dst>>6)
constexpr int G1     = 256;       // partition blocks
constexpr int CHUNK1 = NE / G1;   // 2500 edges per partition block
constexpr int CAPB   = 64;        // per (block,bucket) fragment cap (mean 16, +12 sigma)
constexpr int LCAP   = 5120;      // place LDS record cache (bucket mean 4076, +16 sigma)
}

typedef __attribute__((ext_vector_type(8))) short short8;
typedef __attribute__((ext_vector_type(4))) float f32x4;

__device__ __forceinline__ ushort f2bf(float f) {
    uint u = __float_as_uint(f);
    uint r = u + 0x7FFFu + ((u >> 16) & 1u);   // RNE
    return (ushort)(r >> 16);
}
__device__ __forceinline__ float bf2f(ushort u) {
    return __uint_as_float(((uint)u) << 16);
}
__device__ __forceinline__ float rec_w(uint rec) {
    return __half2float(__ushort_as_half((ushort)(rec & 0xFFFFu)));
}

// ---- CSR pass 1: partition edges into block-private per-bucket fragments ----
// Fused tail: x and W1/W2/W3 fp32 -> bf16 (grid-stride).
__global__ __launch_bounds__(256) void partition_kernel(const int* __restrict__ ei,
                                                        const float* __restrict__ ew,
                                                        uint2* __restrict__ stag,
                                                        int* __restrict__ cnts,
                                                        int* __restrict__ cnts_T,
                                                        const float* __restrict__ x,
                                                        ushort* __restrict__ xb,
                                                        const float* __restrict__ W1,
                                                        ushort* __restrict__ w1b,
                                                        const float* __restrict__ W2,
                                                        ushort* __restrict__ w2b,
                                                        const float* __restrict__ W3,
                                                        ushort* __restrict__ w3b) {
    __shared__ int lcnt[NB];
    const int t = threadIdx.x, g = blockIdx.x;
    for (int i = t; i < NB; i += 256) lcnt[i] = 0;
    __syncthreads();
    const int base = g * CHUNK1;
    for (int i = t; i < CHUNK1; i += 256) {
        const int e = base + i;
        const int dst = ei[NE + e];
        const int src = ei[e];
        const ushort hw = __half_as_ushort(__float2half(ew[e]));
        const int bk = dst >> 6;
        const int idx = atomicAdd(&lcnt[bk], 1);
        if (idx < CAPB)
            stag[((size_t)g * NB + bk) * CAPB + idx] =
                make_uint2(((uint)src << 16) | (uint)hw, (uint)dst);
    }
    __syncthreads();
    for (int i = t; i < NB; i += 256) {
        const int c = min(lcnt[i], CAPB);
        cnts[g * NB + i] = c;          // g-major: read by place foff scan
        cnts_T[i * G1 + g] = c;        // b-major: contiguous rows for bucket totals
    }
    // fused conversions (independent of staging)
    const int gt = g * 256 + t, gs = G1 * 256;
    {
        const int n4 = NN * INC / 4;
        for (int i = gt; i < n4; i += gs) {
            float4 v = ((const float4*)x)[i];
            ushort4 o; o.x = f2bf(v.x); o.y = f2bf(v.y); o.z = f2bf(v.z); o.w = f2bf(v.w);
            ((ushort4*)xb)[i] = o;
        }
    }
    {
        const int n4 = HIDC * INC / 4;
        for (int i = gt; i < n4; i += gs) {
            float4 v = ((const float4*)W1)[i];
            ushort4 o; o.x = f2bf(v.x); o.y = f2bf(v.y); o.z = f2bf(v.z); o.w = f2bf(v.w);
            ((ushort4*)w1b)[i] = o;
        }
    }
    {
        const int n4 = HIDC * HIDC / 4;
        for (int i = gt; i < n4; i += gs) {
            float4 v = ((const float4*)W2)[i];
            ushort4 o; o.x = f2bf(v.x); o.y = f2bf(v.y); o.z = f2bf(v.z); o.w = f2bf(v.w);
            ((ushort4*)w2b)[i] = o;
            float4 v3 = ((const float4*)W3)[i];
            ushort4 o3; o3.x = f2bf(v3.x); o3.y = f2bf(v3.y); o3.z = f2bf(v3.z); o3.w = f2bf(v3.w);
            ((ushort4*)w3b)[i] = o3;
        }
    }
}

// ---- CSR pass 2: per-bucket counting sort (fused bucket prefix) ----
__global__ __launch_bounds__(1024) void place_kernel(const uint2* __restrict__ stag,
                                                     const int* __restrict__ cnts,
                                                     const int* __restrict__ cnts_T,
                                                     int* __restrict__ row_start,
                                                     uint* __restrict__ erec) {
    const int b = blockIdx.x;
    const int t = threadIdx.x;
    __shared__ int part[256];
    __shared__ int foff[G1 + 1];
    __shared__ int h[64];
    __shared__ int curl[64];
    __shared__ uint2 srec[LCAP];

    // Phase 0: bucket totals (contiguous int4 rows) -> exclusive prefix -> bs
    {
        int s = 0;
        if (t < NB) {
            const int4* r = (const int4*)(cnts_T + (size_t)t * G1);
#pragma unroll 8
            for (int i = 0; i < G1 / 4; i++) {
                int4 v = r[i];
                s += v.x + v.y + v.z + v.w;
            }
        }
        if (t < 256) part[t] = s;
        __syncthreads();
        for (int off = 1; off < 256; off <<= 1) {
            int v = 0;
            if (t < 256 && t >= off) v = part[t - off];
            __syncthreads();
            if (t < 256) part[t] += v;
            __syncthreads();
        }
    }
    const int bs = (b == 0) ? 0 : part[b - 1];
    if (b == 0 && t == 0) row_start[NN] = part[NB - 1];
    __syncthreads();

    // Phase 1: fragment offsets within this bucket (scan of cnts[:, b])
    {
        int c = 0;
        if (t < 256) c = cnts[t * NB + b];
        if (t < 256) part[t] = c;
        if (t < 64) h[t] = 0;
        __syncthreads();
        for (int off = 1; off < 256; off <<= 1) {
            int v = 0;
            if (t < 256 && t >= off) v = part[t - off];
            __syncthreads();
            if (t < 256) part[t] += v;
            __syncthreads();
        }
        if (t < 256) foff[t] = part[t] - c;
        if (t == 0) foff[G1] = part[255];
        __syncthreads();
    }
    const int Rb = foff[G1];

    // Phase 2: single global pass: records -> LDS cache + dst_low histogram
    for (int r = t; r < Rb; r += 1024) {
        int lo = 0, hi = G1;
        while (hi - lo > 1) { int mid = (lo + hi) >> 1; if (foff[mid] <= r) lo = mid; else hi = mid; }
        uint2 rec = stag[((size_t)lo * NB + b) * CAPB + (r - foff[lo])];
        if (r < LCAP) srec[r] = rec;
        atomicAdd(&h[rec.y & 63], 1);
    }
    __syncthreads();

    // Phase 3: scan h -> node offsets; emit row_start for this bucket's nodes
    {
        const int hv = (t < 64) ? h[t] : 0;
        if (t < 256) part[t] = (t < 64) ? hv : 0;
        __syncthreads();
        for (int off = 1; off < 64; off <<= 1) {
            int v = 0;
            if (t < 256 && t >= off) v = part[t - off];
            __syncthreads();
            if (t < 256) part[t] += v;
            __syncthreads();
        }
        if (t < 64) {
            const int excl = part[t] - hv;
            const int node = b * 64 + t;
            if (node < NN) row_start[node] = bs + excl;
            curl[t] = excl;
        }
        __syncthreads();
    }

    // Phase 4: place records (LDS-resident; global fallback for overflow)
    for (int r = t; r < Rb; r += 1024) {
        uint2 rec;
        if (r < LCAP) rec = srec[r];
        else {
            int lo = 0, hi = G1;
            while (hi - lo > 1) { int mid = (lo + hi) >> 1; if (foff[mid] <= r) lo = mid; else hi = mid; }
            rec = stag[((size_t)lo * NB + b) * CAPB + (r - foff[lo])];
        }
        const int pos = bs + atomicAdd(&curl[rec.y & 63], 1);
        erec[pos] = rec.x;
    }
}

// ---- aggregation gather, full row (used for F=128) ----
template <int F>
__global__ __launch_bounds__(256) void gather_bf16_kernel(const int* __restrict__ row_start,
                                                          const uint* __restrict__ erec,
                                                          const ushort* __restrict__ x,
                                                          ushort* __restrict__ out) {
    constexpr int VEC = F / 64;
    constexpr int U = 12;
    const int n = blockIdx.x * 4 + (threadIdx.x >> 6);
    const int lane = threadIdx.x & 63;
    if (n >= NN) return;
    const int beg = row_start[n];
    const int end = row_start[n + 1];
    const size_t loff = (size_t)lane * VEC;

    float acc[VEC];
    {
        ushort v[VEC];
        if (VEC == 4) *(ushort4*)v = *(const ushort4*)(x + (size_t)n * F + loff);
        else          *(ushort2*)v = *(const ushort2*)(x + (size_t)n * F + loff);
#pragma unroll
        for (int i = 0; i < VEC; i++) acc[i] = bf2f(v[i]);
    }

    int e = beg;
    for (; e + U <= end; e += U) {
        uint rec[U];
#pragma unroll
        for (int u = 0; u < U; u++) rec[u] = erec[e + u];
        ushort v[U][VEC];
#pragma unroll
        for (int u = 0; u < U; u++) {
            const ushort* r = x + (size_t)(rec[u] >> 16) * F + loff;
            if (VEC == 4) *(ushort4*)v[u] = *(const ushort4*)r;
            else          *(ushort2*)v[u] = *(const ushort2*)r;
        }
#pragma unroll
        for (int u = 0; u < U; u++) {
            const float w = rec_w(rec[u]);
#pragma unroll
            for (int i = 0; i < VEC; i++) acc[i] += w * bf2f(v[u][i]);
        }
    }
    for (; e < end; e++) {
        uint rec = erec[e];
        const float w = rec_w(rec);
        ushort v[VEC];
        const ushort* r = x + (size_t)(rec >> 16) * F + loff;
        if (VEC == 4) *(ushort4*)v = *(const ushort4*)r;
        else          *(ushort2*)v = *(const ushort2*)r;
#pragma unroll
        for (int i = 0; i < VEC; i++) acc[i] += w * bf2f(v[i]);
    }

    ushort o[VEC];
#pragma unroll
    for (int i = 0; i < VEC; i++) o[i] = f2bf(acc[i]);
    if (VEC == 4) *(ushort4*)(out + (size_t)n * F + loff) = *(ushort4*)o;
    else          *(ushort2*)(out + (size_t)n * F + loff) = *(ushort2*)o;
}

// ---- F=256 gather, XCD-parity channel-half swizzle ----
// half = blockIdx.x & 1: with cyclic workgroup->XCD assignment, half 0 lands
// on even XCDs and half 1 on odd -> each XCD's 4-MB L2 holds only a 2.56-MB
// channel slice (performance heuristic only; correctness independent).
__global__ __launch_bounds__(256) void gather_bf16_half_kernel(const int* __restrict__ row_start,
                                                               const uint* __restrict__ erec,
                                                               const ushort* __restrict__ x,
                                                               ushort* __restrict__ out) {
    constexpr int U = 16;
    const int half = blockIdx.x & 1;
    const int n = (blockIdx.x >> 1) * 4 + (threadIdx.x >> 6);
    const int lane = threadIdx.x & 63;
    if (n >= NN) return;
    const int beg = row_start[n];
    const int end = row_start[n + 1];
    const size_t loff = (size_t)half * 128 + lane * 2;

    float acc0, acc1;
    {
        ushort2 v = *(const ushort2*)(x + (size_t)n * HIDC + loff);
        acc0 = bf2f(v.x);
        acc1 = bf2f(v.y);
    }

    int e = beg;
    for (; e + U <= end; e += U) {
        uint rec[U];
#pragma unroll
        for (int u = 0; u < U; u++) rec[u] = erec[e + u];
        ushort2 v[U];
#pragma unroll
        for (int u = 0; u < U; u++)
            v[u] = *(const ushort2*)(x + (size_t)(rec[u] >> 16) * HIDC + loff);
#pragma unroll
        for (int u = 0; u < U; u++) {
            const float w = rec_w(rec[u]);
            acc0 += w * bf2f(v[u].x);
            acc1 += w * bf2f(v[u].y);
        }
    }
    for (; e < end; e++) {
        uint rec = erec[e];
        const float w = rec_w(rec);
        ushort2 v = *(const ushort2*)(x + (size_t)(rec >> 16) * HIDC + loff);
        acc0 += w * bf2f(v.x);
        acc1 += w * bf2f(v.y);
    }

    ushort2 o;
    o.x = f2bf(acc0);
    o.y = f2bf(acc1);
    *(ushort2*)(out + (size_t)n * HIDC + loff) = o;
}

// ---- MFMA bf16 GEMM: C[M,256] = relu(A[M,K] @ W[256,K]^T + bias), bf16 out ----
// W pre-converted to bf16; staged as uint4.
template <int K>
__global__ __launch_bounds__(256) void mfma_gemm_kernel(const ushort* __restrict__ A,
                                                        const ushort* __restrict__ Wb,
                                                        const float* __restrict__ bias,
                                                        ushort* __restrict__ C, int M) {
    constexpr int LDW = K + 8;
    __shared__ ushort Ws[64 * LDW];
    const int tid = threadIdx.x;
    const int bm = blockIdx.x * 128;
    const int bn = blockIdx.y * 64;

    constexpr int CPR = K / 8;
    for (int idx = tid; idx < 64 * CPR; idx += 256) {
        int r = idx / CPR, c = idx % CPR;
        uint4 v = *(const uint4*)(Wb + (size_t)(bn + r) * K + c * 8);
        *(uint4*)(&Ws[r * LDW + c * 8]) = v;
    }
    __syncthreads();

    const int wave = tid >> 6;
    const int lane = tid & 63;
    const int lrow = lane & 15;
    const int lq   = lane >> 4;
    const int m0 = bm + wave * 32;

    f32x4 acc[2][4] = {};
    const int r0 = min(m0 + lrow, M - 1);
    const int r1 = min(m0 + 16 + lrow, M - 1);

    for (int k0 = 0; k0 < K; k0 += 32) {
        const int kk = k0 + lq * 8;
        short8 a0 = *(const short8*)(A + (size_t)r0 * K + kk);
        short8 a1 = *(const short8*)(A + (size_t)r1 * K + kk);
        short8 b[4];
#pragma unroll
        for (int j = 0; j < 4; j++)
            b[j] = *(const short8*)(&Ws[(j * 16 + lrow) * LDW + kk]);
#pragma unroll
        for (int j = 0; j < 4; j++) {
            acc[0][j] = __builtin_amdgcn_mfma_f32_16x16x32_bf16(a0, b[j], acc[0][j], 0, 0, 0);
            acc[1][j] = __builtin_amdgcn_mfma_f32_16x16x32_bf16(a1, b[j], acc[1][j], 0, 0, 0);
        }
    }

#pragma unroll
    for (int sub = 0; sub < 2; sub++) {
#pragma unroll
        for (int j = 0; j < 4; j++) {
            const int gn = bn + j * 16 + lrow;
            const float bv = bias[gn];
#pragma unroll
            for (int i = 0; i < 4; i++) {
                const int gm = m0 + sub * 16 + lq * 4 + i;
                if (gm < M) {
                    float v = acc[sub][j][i] + bv;
                    v = fmaxf(v, 0.0f);
                    C[(size_t)gm * HIDC + gn] = f2bf(v);
                }
            }
        }
    }
}

__device__ __forceinline__ int lower_bound_batch(const int* __restrict__ batch, int val) {
    int lo = 0, hi = NN;
    while (lo < hi) {
        int mid = (lo + hi) >> 1;
        if (batch[mid] < val) lo = mid + 1;
        else hi = mid;
    }
    return lo;
}

// ---- segmented mean-pool stage 1: partial sums over bf16 h ----
__global__ __launch_bounds__(256) void pool_partial_kernel(const ushort* __restrict__ h,
                                                           const int* __restrict__ batch,
                                                           float* __restrict__ partials) {
    const int g = blockIdx.x;
    const int p = blockIdx.y;
    const int c = threadIdx.x;
    const int lo = lower_bound_batch(batch, g);
    const int hi = lower_bound_batch(batch, g + 1);
    const int cnt = hi - lo;
    const int chunk = (cnt + PP - 1) / PP;
    const int n0 = lo + p * chunk;
    const int n1 = min(hi, n0 + chunk);
    float sum = 0.0f;
    for (int n = n0; n < n1; n++) sum += bf2f(h[(size_t)n * HIDC + c]);
    partials[((size_t)g * PP + p) * HIDC + c] = sum;
}

// ---- stage 2: reduce partials, mean, head linear (fp32) ----
__global__ __launch_bounds__(256) void head_kernel(const float* __restrict__ partials,
                                                   const int* __restrict__ batch,
                                                   const float* __restrict__ Wl,
                                                   const float* __restrict__ bl,
                                                   float* __restrict__ out) {
    __shared__ float s[HIDC];
    const int g = blockIdx.x;
    const int c = threadIdx.x;
    const int lo = lower_bound_batch(batch, g);
    const int hi = lower_bound_batch(batch, g + 1);
    const float inv = 1.0f / fmaxf((float)(hi - lo), 1.0f);
    float sum = 0.0f;
#pragma unroll
    for (int p = 0; p < PP; p++) sum += partials[((size_t)g * PP + p) * HIDC + c];
    s[c] = sum * inv;
    __syncthreads();
    if (c < OUTC) {
        float acc = bl[c];
        for (int k = 0; k < HIDC; k++) acc += s[k] * Wl[(size_t)c * HIDC + k];
        out[(size_t)g * OUTC + c] = acc;
    }
}

extern "C" void kernel_launch(void* const* d_in, const int* in_sizes, int n_in,
                              void* d_out, int out_size, void* d_ws, size_t ws_size,
                              hipStream_t stream) {
    const float* x     = (const float*)d_in[0];
    const int*   ei    = (const int*)d_in[1];
    const int*   batch = (const int*)d_in[2];
    const float* ew    = (const float*)d_in[3];
    const float* W1    = (const float*)d_in[4];
    const float* b1    = (const float*)d_in[5];
    const float* W2    = (const float*)d_in[6];
    const float* b2    = (const float*)d_in[7];
    const float* W3    = (const float*)d_in[8];
    const float* b3    = (const float*)d_in[9];
    const float* Wl    = (const float*)d_in[10];
    const float* bl    = (const float*)d_in[11];

    // ---- workspace layout ----
    char* p = (char*)d_ws;
    uint2*  stag   = (uint2*)p;  p += (size_t)G1 * NB * CAPB * 8;   // 20.6 MB
    ushort* xb     = (ushort*)p; p += (size_t)NN * INC * 2;
    ushort* agg128 = (ushort*)p; p += (size_t)NN * INC * 2;
    ushort* agg256 = (ushort*)p; p += (size_t)NN * HIDC * 2;
    ushort* h      = (ushort*)p; p += (size_t)NN * HIDC * 2;
    ushort* w1b    = (ushort*)p; p += (size_t)HIDC * INC * 2;
    ushort* w2b    = (ushort*)p; p += (size_t)HIDC * HIDC * 2;
    ushort* w3b    = (ushort*)p; p += (size_t)HIDC * HIDC * 2;
    uint*   erec   = (uint*)p;   p += (size_t)NE * 4;
    float*  partials = (float*)p; p += (size_t)NG * PP * HIDC * 4;
    int*    cnts   = (int*)p;    p += (size_t)G1 * NB * 4;
    int*    cnts_T = (int*)p;    p += (size_t)NB * G1 * 4;
    int*    row_start = (int*)p; p += 40016;

    // ---- CSR build: radix partition (per call) ----
    partition_kernel<<<G1, 256, 0, stream>>>(ei, ew, stag, cnts, cnts_T, x, xb,
                                             W1, w1b, W2, w2b, W3, w3b);
    place_kernel<<<NB, 1024, 0, stream>>>(stag, cnts, cnts_T, row_start, erec);

    const int gather_grid = (NN + 3) / 4;
    dim3 gemm_grid((NN + 127) / 128, HIDC / 64);

    // ---- layer 1 (K=128) ----
    gather_bf16_kernel<INC><<<gather_grid, 256, 0, stream>>>(row_start, erec, xb, agg128);
    mfma_gemm_kernel<INC><<<gemm_grid, 256, 0, stream>>>(agg128, w1b, b1, h, NN);

    // ---- layer 2 (K=256): XCD-parity half swizzle ----
    gather_bf16_half_kernel<<<gather_grid * 2, 256, 0, stream>>>(row_start, erec, h, agg256);
    mfma_gemm_kernel<HIDC><<<gemm_grid, 256, 0, stream>>>(agg256, w2b, b2, h, NN);

    // ---- layer 3 (K=256) ----
    gather_bf16_half_kernel<<<gather_grid * 2, 256, 0, stream>>>(row_start, erec, h, agg256);
    mfma_gemm_kernel<HIDC><<<gemm_grid, 256, 0, stream>>>(agg256, w3b, b3, h, NN);

    // ---- global mean pool + head ----
    pool_partial_kernel<<<dim3(NG, PP), 256, 0, stream>>>(h, batch, partials);
    head_kernel<<<NG, 256, 0, stream>>>(partials, batch, Wl, bl, (float*)d_out);
}